// Round 1
// 60.664 us; speedup vs baseline: 1.6217x; 1.6217x over previous
//
#include <hip/hip_runtime.h>

#define H 512
#define W 512
#define NPIX (H * W)
#define BIG_I 1073741824   // 2^30
#define BIG_F 1.0e6f
#define INF30 1.0e30f

// ---- workspace layout ----
// [0, NPIX) int32       : lab  (union-find forest)
// [NPIX, 2*NPIX) float  : dist (row-pass result)
// then (64B aligned): Scal, Asoa[256], then lab2[NPIX] (final labels)
struct Scal {
  float soa;
  unsigned int min_bits;
  float cluster;
  unsigned int done;
  int both;
  float r0, r1;
  int sl, p0;
  int skip;          // both && (start component == end component) -> min_d == 0 exactly
};

// ================= union-find (min-index roots) =================
__device__ __forceinline__ int rep(int* lab, int v) {
  int cur = lab[v];
  if (cur == v) return v;
  int prev = v, next;
  while (cur > (next = lab[cur])) { lab[prev] = next; prev = cur; cur = next; }
  return cur;
}
__device__ __forceinline__ void unite(int* lab, int a, int b) {
  int ra = rep(lab, a), rb = rep(lab, b);
  while (ra != rb) {
    if (ra < rb) { int t = ra; ra = rb; rb = t; }
    int old = atomicCAS(&lab[ra], ra, rb);
    if (old == ra) break;
    ra = rep(lab, old);
    rb = rep(lab, rb);
  }
}
// path-halving walk: writes only ancestors (monotone), safe concurrent w/ readers
__device__ __forceinline__ int root_ph(int* lab, int v) {
  int p = lab[v];
  if (p == v) return v;
  int gp = lab[p];
  while (p != gp) {
    lab[v] = gp;     // benign race: gp is an ancestor of v
    v = p; p = gp; gp = lab[p];
  }
  return p;
}
// run start column of bit c in mask (bit c must be set)
__device__ __forceinline__ int runstart(unsigned m, int c) {
  unsigned z = ~m & ((1u << c) - 1u);
  return z ? (32 - __clz((int)z)) : 0;
}

// ---- 0: scalar prologue. both/r0/r1 depend only on img at two pixels.  ----
// If !both, ALL outputs are the fallback scalar: the entire CCL/DT pipeline is
// dead and downstream kernels early-exit.
__global__ void k_pre(const float* __restrict__ img, const int* __restrict__ pts,
                      Scal* __restrict__ s, float* __restrict__ out) {
  if (threadIdx.x != 0) return;
  int p0 = pts[0] * W + pts[1];
  int p1 = pts[2] * W + pts[3];
  float r0 = img[p0], r1 = img[p1];
  int both = (rintf(r0) > 0.5f) && (rintf(r1) > 0.5f);
  s->both = both;
  s->r0 = r0;
  s->r1 = r1;
  s->p0 = p0;
  s->min_bits = __float_as_uint(BIG_F);
  s->cluster = 0.0f;
  s->done = 0u;
  s->skip = 0;
  if (!both) {
    float fb = (2.0f - (r0 + r1)) * 100.0f;
    out[0] = fb; out[1] = fb; out[2] = fb;
  }
}

// ---- 1: per-tile (32x32) LDS CCL (run-based, pruned unions) + soa partial ----
__global__ __launch_bounds__(256) void k_local(const float* __restrict__ img,
                                               int* __restrict__ lab,
                                               float* __restrict__ Asoa,
                                               const Scal* __restrict__ s) {
  if (!s->both) return;                        // labels/soa dead when !both
  __shared__ int sl[1024];           // only run-start slots are ever used
  __shared__ unsigned rmask[32];
  __shared__ float red[4];
  const int t = threadIdx.x, b = blockIdx.x;
  const int tileX = (b & 15) * 32;
  const int tileY = (b >> 4) * 32;
  const int r = t >> 3, c0 = (t & 7) * 4;     // thread owns 4 px of tile-row r
  const float4 x4 = *(const float4*)(img + (tileY + r) * W + tileX + c0);
  float acc = 4.0f - (x4.x + x4.y + x4.z + x4.w);
  unsigned nib = (rintf(x4.x) > 0.5f ? 1u : 0u) | (rintf(x4.y) > 0.5f ? 2u : 0u)
               | (rintf(x4.z) > 0.5f ? 4u : 0u) | (rintf(x4.w) > 0.5f ? 8u : 0u);
  unsigned m = nib << c0;                      // full row mask via OR over lanes 8r..8r+7
  m |= __shfl_xor(m, 1, 64);
  m |= __shfl_xor(m, 2, 64);
  m |= __shfl_xor(m, 4, 64);
  if ((t & 7) == 0) rmask[r] = m;
  unsigned startM = m & ~(m << 1);
  #pragma unroll
  for (int k = 0; k < 4; ++k) {                // init union-find at run starts only
    int c = c0 + k;
    if ((startM >> c) & 1u) sl[(r << 5) + c] = (r << 5) + c;
  }
  __syncthreads();
  if (r > 0) {
    unsigned ma = rmask[r - 1];
    unsigned upM = m & ma & (~(m << 1) | ~(ma << 1));      // one unite per (run, above-run) pair
    unsigned dL  = startM & (ma << 1) & ~ma;
    unsigned dR  = (m & ~(m >> 1)) & (ma >> 1) & ~ma;
    #pragma unroll
    for (int k = 0; k < 4; ++k) {
      int c = c0 + k;
      int myS = (r << 5) + runstart(m, c);
      if ((upM >> c) & 1u) unite(sl, myS, ((r - 1) << 5) + runstart(ma, c));
      if ((dL  >> c) & 1u) unite(sl, myS, ((r - 1) << 5) + runstart(ma, c - 1));
      if ((dR  >> c) & 1u) unite(sl, myS, ((r - 1) << 5) + c + 1);
    }
  }
  __syncthreads();
  int o[4];
  #pragma unroll
  for (int k = 0; k < 4; ++k) {
    int c = c0 + k;
    if ((m >> c) & 1u) {
      int rt = rep(sl, (r << 5) + runstart(m, c));
      o[k] = (tileY + (rt >> 5)) * W + tileX + (rt & 31);
    } else o[k] = BIG_I;
  }
  *(int4*)(lab + (tileY + r) * W + tileX + c0) = make_int4(o[0], o[1], o[2], o[3]);
  for (int off = 32; off; off >>= 1) acc += __shfl_down(acc, off, 64);
  if ((t & 63) == 0) red[t >> 6] = acc;
  __syncthreads();
  if (t == 0) Asoa[b] = red[0] + red[1] + red[2] + red[3];
}

// ---- 2: border merge (run-deduped) + soa reduce (block 60) ----
// Dedupe rule: skip a unite iff its (label,label) pair is identical to the
// immediately-preceding candidate in the boundary enumeration (the first of
// each run of identical pairs is always issued -> coverage preserved; unions
// are commutative/idempotent so cross-wave order is irrelevant).
__global__ void k_border(int* __restrict__ lab, const float* __restrict__ Asoa,
                         Scal* __restrict__ s) {
  if (!s->both) return;
  int t = threadIdx.x;
  int lane = t & 63;
  int gid = blockIdx.x * 256 + t;
  if (gid < 7680) {                            // horizontal boundary rows i=32,64,...
    int bb = gid >> 9, j = gid & 511;
    int i = (bb + 1) * 32;
    int p = i * W + j, q = p - W;
    int a  = lab[p];                           // raw labels (tile roots)
    int u0 = lab[q];
    int um = (j > 0)   ? lab[q - 1] : BIG_I;
    int up = (j < 511) ? lab[q + 1] : BIG_I;
    int a_prev = __shfl_up(a, 1, 64);
    if (lane == 0) a_prev = (j > 0) ? lab[p - 1] : BIG_I;
    if (a != BIG_I) {
      // E_m: covered by left pixel's E_0 when same lower run
      if (um != BIG_I && a != a_prev) unite(lab, a, um);
      // E_0: identical to own E_m when upper label unchanged
      if (u0 != BIG_I && u0 != um) unite(lab, a, u0);
      // E_p: identical to own E_0 (or E_m when u0 is bg)
      if (up != BIG_I && up != u0 && !(u0 == BIG_I && up == um)) unite(lab, a, up);
    }
  } else if (gid < 15360) {                    // vertical boundary cols j=32,64,...
    int t2 = gid - 7680;
    int bb = t2 >> 9, i = t2 & 511;
    int j = (bb + 1) * 32;
    int p = i * W + j;
    int lp = lab[p], ll = lab[p - 1];
    int lpp = __shfl_up(lp, 1, 64);            // row i-1: lab[p-W]
    int llp = __shfl_up(ll, 1, 64);            // row i-1: lab[p-W-1]
    if (lane == 0) {
      lpp = (i > 0) ? lab[p - W] : BIG_I;
      llp = (i > 0) ? lab[p - W - 1] : BIG_I;
    }
    bool fgp = lp != BIG_I, fgl = ll != BIG_I;
    // V edge: covered by row i-1's V when both labels unchanged
    if (fgp && fgl && !(lp == lpp && ll == llp)) unite(lab, lp, ll);
    if ((i & 31) && i > 0) {                   // diagonals (i%32==0 covered by horiz pass)
      // d1 = (lp, lab[p-W-1]) ; covered by V(i-1) when lp==lpp
      if (fgp && llp != BIG_I && lp != lpp) unite(lab, lp, llp);
      // d2 = (ll, lab[p-W])   ; covered by V(i-1) when ll==llp
      if (fgl && lpp != BIG_I && ll != llp) unite(lab, ll, lpp);
    }
  } else if (t < 64) {                         // block 60: reduce soa partials
    float a = Asoa[t] + Asoa[t + 64] + Asoa[t + 128] + Asoa[t + 192];
    for (int off = 32; off; off >>= 1) a += __shfl_down(a, off, 64);
    if (t == 0) s->soa = a;
  }
}

// ---- 3: flatten + cluster partial; row min-plus scan only when sl != el ----
// 256 blocks x 128 threads; one wave per row.
// If sl == el (one component holds both points), start_mask is a subset of the
// DT zero set -> dist == 0 on it and at p0 -> min_d == 0 exactly. The whole
// row/col DT (and lab2/dist stores) is dead; only cluster/soa survive.
__global__ __launch_bounds__(128) void k_dt_rows(int* __restrict__ lab,
                                                 int* __restrict__ lab2,
                                                 const float* __restrict__ img,
                                                 const int* __restrict__ pts,
                                                 Scal* __restrict__ s,
                                                 float* __restrict__ dist) {
  if (!s->both) return;
  int lane = threadIdx.x & 63;
  int row = blockIdx.x * 2 + (threadIdx.x >> 6);
  int el = -1, sl2 = -1;
  if (lane == 0) {
    int p0 = pts[0] * W + pts[1], p1 = pts[2] * W + pts[3];
    el = root_ph(lab, lab[p1]);                // both==1 -> labels valid
    sl2 = root_ph(lab, lab[p0]);
    if (blockIdx.x == 0 && threadIdx.x == 0) {
      s->sl = sl2;
      s->skip = (el == sl2);
    }
  }
  el = __shfl(el, 0, 64);
  sl2 = __shfl(sl2, 0, 64);
  const bool skip = (el == sl2);
  const int4* lp = (const int4*)(lab + row * W) + lane * 2;
  int4 a = lp[0], bq = lp[1];
  int v[8] = {a.x, a.y, a.z, a.w, bq.x, bq.y, bq.z, bq.w};
  int psrc = -1, proot = -1;
  #pragma unroll
  for (int k = 0; k < 8; ++k) {                // flatten w/ memo + halving
    if (v[k] == BIG_I) continue;
    if (v[k] == psrc) { v[k] = proot; continue; }
    psrc = v[k];
    proot = root_ph(lab, v[k]);
    v[k] = proot;
  }
  if (!skip) {                                 // lab2 only consumed by col pass
    int4* l2 = (int4*)(lab2 + row * W) + lane * 2;
    l2[0] = make_int4(v[0], v[1], v[2], v[3]);
    l2[1] = make_int4(v[4], v[5], v[6], v[7]);
  }
  // cluster partial: sum img over start-component pixels of this row
  const float4* ip = (const float4*)(img + row * W) + lane * 2;
  float4 i0q = ip[0], i1q = ip[1];
  float cv = 0.0f;
  if (v[0] == sl2) cv += i0q.x;
  if (v[1] == sl2) cv += i0q.y;
  if (v[2] == sl2) cv += i0q.z;
  if (v[3] == sl2) cv += i0q.w;
  if (v[4] == sl2) cv += i1q.x;
  if (v[5] == sl2) cv += i1q.y;
  if (v[6] == sl2) cv += i1q.z;
  if (v[7] == sl2) cv += i1q.w;
  for (int off = 32; off; off >>= 1) cv += __shfl_down(cv, off, 64);
  if (lane == 0 && cv != 0.0f) atomicAdd(&s->cluster, cv);
  if (skip) return;                            // min_d == 0 exactly: no DT needed
  // row min-plus scan
  float d[8];
  #pragma unroll
  for (int k = 0; k < 8; ++k) d[k] = (v[k] == el) ? 0.0f : BIG_F;
  int j0 = lane * 8;
  float pf[8], sb[8];
  float m = INF30;
  #pragma unroll
  for (int k = 0; k < 8; ++k) { m = fminf(m, d[k] - (float)(j0 + k)); pf[k] = m; }
  float tf = m;
  m = INF30;
  #pragma unroll
  for (int k = 7; k >= 0; --k) { m = fminf(m, d[k] + (float)(j0 + k)); sb[k] = m; }
  float tb = m;
  float vv = tf;
  #pragma unroll
  for (int off = 1; off < 64; off <<= 1) {
    float u = __shfl_up(vv, off, 64);
    if (lane >= off) vv = fminf(vv, u);
  }
  float ef = __shfl_up(vv, 1, 64); if (lane == 0) ef = INF30;
  vv = tb;
  #pragma unroll
  for (int off = 1; off < 64; off <<= 1) {
    float u = __shfl_down(vv, off, 64);
    if (lane < 64 - off) vv = fminf(vv, u);
  }
  float eb = __shfl_down(vv, 1, 64); if (lane == 63) eb = INF30;
  float o[8];
  #pragma unroll
  for (int k = 0; k < 8; ++k) {
    float j = (float)(j0 + k);
    o[k] = fminf(j + fminf(ef, pf[k]), -j + fminf(eb, sb[k]));
  }
  float4* dp = (float4*)(dist + row * W) + lane * 2;
  dp[0] = make_float4(o[0], o[1], o[2], o[3]);
  dp[1] = make_float4(o[4], o[5], o[6], o[7]);
}

// ---- 4: column DT (two-level scan via LDS) + masked min + finalize ----
// 32 blocks x 512 threads; block owns 16 columns; thread = (32 segments x 16 rows).
__global__ __launch_bounds__(512) void k_dt_colfin(
    const float* __restrict__ dist, const int* __restrict__ lab2,
    Scal* __restrict__ s, float* __restrict__ out) {
  if (!s->both) return;                        // k_pre already wrote fallback out
  if (s->skip) {                               // min_d == 0 exactly; finalize only
    if (threadIdx.x == 0) {
      unsigned old = atomicAdd(&s->done, 1u);
      if (old == gridDim.x - 1) {
        out[0] = (2.0f - (s->r0 + s->r1)) * 100.0f;
        out[1] = 0.0f;                         // min_d * soa * 10 * soa == 0
        float cl = atomicAdd(&s->cluster, 0.0f);
        out[2] = cl * 90.0f;
      }
    }
    return;
  }
  __shared__ float laf[32][16], lbb[32][16];
  __shared__ float smin[8];
  int t = threadIdx.x;
  int sg = t >> 4, c = t & 15;
  int j = blockIdx.x * 16 + c;
  int i0 = sg * 16;
  float rr[16];
  float fa = INF30, fb = INF30;
  #pragma unroll
  for (int il = 0; il < 16; ++il) {
    rr[il] = dist[(i0 + il) * W + j];
    float fi = (float)(i0 + il);
    fa = fminf(fa, rr[il] - fi);
    fb = fminf(fb, rr[il] + fi);
  }
  laf[sg][c] = fa;
  lbb[sg][c] = fb;
  __syncthreads();
  float cf = INF30, cb = INF30;
  #pragma unroll
  for (int bb = 0; bb < 32; ++bb) {
    if (bb < sg) cf = fminf(cf, laf[bb][c]);
    if (bb > sg) cb = fminf(cb, lbb[bb][c]);
  }
  int slv = s->sl;
  int p0 = s->p0;
  float ff[16];
  float m = cf;
  #pragma unroll
  for (int il = 0; il < 16; ++il) {
    float fi = (float)(i0 + il);
    m = fminf(m, rr[il] - fi);
    ff[il] = fi + m;
  }
  m = cb;
  float dv = BIG_F;
  #pragma unroll
  for (int il = 15; il >= 0; --il) {           // final dist consumed in-register
    int pix = (i0 + il) * W + j;
    float fi = (float)(i0 + il);
    m = fminf(m, rr[il] + fi);
    float o = fminf(ff[il], m - fi);
    if (lab2[pix] == slv) dv = fminf(dv, o);
    if (pix == p0) dv = fminf(dv, o);          // dist[p0] term, mask-independent
  }
  for (int off = 32; off; off >>= 1)
    dv = fminf(dv, __shfl_down(dv, off, 64));
  if ((t & 63) == 0) smin[t >> 6] = dv;
  __syncthreads();
  if (t == 0) {
    float mm = INF30;
    #pragma unroll
    for (int w = 0; w < 8; ++w) mm = fminf(mm, smin[w]);
    atomicMin(&s->min_bits, __float_as_uint(mm));  // dist >= 0: uint order == float order
    __threadfence();
    unsigned old = atomicAdd(&s->done, 1u);
    if (old == gridDim.x - 1) {
      float fallback = (2.0f - (s->r0 + s->r1)) * 100.0f;
      out[0] = fallback;
      float min_d = __uint_as_float(atomicOr(&s->min_bits, 0u));
      float cl = atomicAdd(&s->cluster, 0.0f);
      float soa = s->soa;
      out[1] = min_d * soa * 10.0f * soa;
      out[2] = cl * 90.0f;
    }
  }
}

extern "C" void kernel_launch(void* const* d_in, const int* in_sizes, int n_in,
                              void* d_out, int out_size, void* d_ws, size_t ws_size,
                              hipStream_t stream) {
  const float* img = (const float*)d_in[0] + 3 * NPIX;   // result_given[3,0]
  const int* pts = (const int*)d_in[1] + 3 * 4;          // points_given[3]
  float* out = (float*)d_out;

  int* lab = (int*)d_ws;
  float* dist = (float*)d_ws + NPIX;
  char* base = (char*)d_ws + (size_t)2 * NPIX * 4;
  Scal* s = (Scal*)base;
  float* Asoa = (float*)(base + 64);
  int* lab2 = (int*)(base + 64 + 1024);

  k_pre<<<1, 64, 0, stream>>>(img, pts, s, out);
  k_local<<<256, 256, 0, stream>>>(img, lab, Asoa, s);
  k_border<<<61, 256, 0, stream>>>(lab, Asoa, s);
  k_dt_rows<<<H / 2, 128, 0, stream>>>(lab, lab2, img, pts, s, dist);
  k_dt_colfin<<<32, 512, 0, stream>>>(dist, lab2, s, out);
}